// Round 6
// baseline (147.260 us; speedup 1.0000x reference)
//
#include <hip/hip_runtime.h>
#include <stdint.h>

#define NPRED   16384
#define NGT     128
#define KSEL    64
#define CAP     384
#define THREADS 256
#define T0      0.055f     // initial radius (E[C] ~ 155 for uniform data)

typedef unsigned long long u64;

// Outputs (float32, concatenated): ious[16*128*64], mask[...], k_idx[...]
#define OUT_IOUS 0
#define OUT_MASK (16 * NGT * KSEL)
#define OUT_KIDX (2 * 16 * NGT * KSEL)

// ws: packed centers, [16][8192] float4 = (cx0,cy0,cx1,cy1) pairs. 2 MiB.
#define WS_NEEDED (16 * (NPRED / 2) * 16)

// numpy-exact pairwise sum of 64 per-lane values (n=64: 8 strided partials,
// then ((r0+r1)+(r2+r3)) + ((r4+r5)+(r6+r7))). All lanes return the sum.
// Validated bit-exact (absmax=0) in R2-R5.
__device__ __forceinline__ float npsum64(float v, int lane) {
    const int j = lane & 7;
    float r = __shfl(v, j, 64);                       // a[j]
    #pragma unroll
    for (int k = 1; k < 8; ++k)
        r = __fadd_rn(r, __shfl(v, j + 8 * k, 64));   // += a[j+8k], in order
    const float r0 = __shfl(r, 0, 64), r1 = __shfl(r, 1, 64),
                r2 = __shfl(r, 2, 64), r3 = __shfl(r, 3, 64),
                r4 = __shfl(r, 4, 64), r5 = __shfl(r, 5, 64),
                r6 = __shfl(r, 6, 64), r7 = __shfl(r, 7, 64);
    return __fadd_rn(__fadd_rn(__fadd_rn(r0, r1), __fadd_rn(r2, r3)),
                     __fadd_rn(__fadd_rn(r4, r5), __fadd_rn(r6, r7)));
}

// Shared epilogue: IoU, mean+std(ddof=1) threshold, mask — numpy-exact f32.
// Executed by lanes 0..63 of wave 0. Keys in topk[0..63].
__device__ __forceinline__ void epilogue(
    const u64* topk, const float* pb, int task, int lane,
    float gcx, float gcy, float gw, float gh, float* out)
{
    const u64 key = topk[lane];
    const int idx = (int)(key & (u64)(NPRED - 1));

    const float gx1 = __fsub_rn(gcx, __fmul_rn(0.5f, gw));
    const float gy1 = __fsub_rn(gcy, __fmul_rn(0.5f, gh));
    const float gx2 = __fadd_rn(gcx, __fmul_rn(0.5f, gw));
    const float gy2 = __fadd_rn(gcy, __fmul_rn(0.5f, gh));

    const float4 kb = *reinterpret_cast<const float4*>(pb + (size_t)idx * 4);
    const float kcx = kb.x, kcy = kb.y;
    float kx1 = __fsub_rn(kb.x, __fmul_rn(0.5f, kb.z));
    float ky1 = __fsub_rn(kb.y, __fmul_rn(0.5f, kb.w));
    float kx2 = __fadd_rn(kb.x, __fmul_rn(0.5f, kb.z));
    float ky2 = __fadd_rn(kb.y, __fmul_rn(0.5f, kb.w));
    float ltx = fmaxf(gx1, kx1), lty = fmaxf(gy1, ky1);
    float rbx = fminf(gx2, kx2), rby = fminf(gy2, ky2);
    float wx = fmaxf(__fsub_rn(rbx, ltx), 0.0f);
    float wy = fmaxf(__fsub_rn(rby, lty), 0.0f);
    float inter = __fmul_rn(wx, wy);
    float ag = __fmul_rn(__fsub_rn(gx2, gx1), __fsub_rn(gy2, gy1));
    float ak = __fmul_rn(__fsub_rn(kx2, kx1), __fsub_rn(ky2, ky1));
    float uni = __fsub_rn(__fadd_rn(ag, ak), inter);
    const float iou = __fdiv_rn(inter, uni);

    const float mean = __fdiv_rn(npsum64(iou, lane), 64.0f);
    const float dd   = __fsub_rn(iou, mean);
    const float var  = __fdiv_rn(npsum64(__fmul_rn(dd, dd), lane), 63.0f);
    const float thr  = __fadd_rn(mean, __fsqrt_rn(var));

    const bool inside = (gx1 <= kcx) && (kcx <= gx2) && (gy1 <= kcy) && (kcy <= gy2);
    const bool m = (iou >= thr) && inside;

    const int o = task * KSEL + lane;
    out[OUT_IOUS + o] = iou;
    out[OUT_MASK + o] = m ? 1.0f : 0.0f;
    out[OUT_KIDX + o] = (float)idx;
}

// ---- Kernel 1: pack pred centers densely: cxy4[j] = (cx2j,cy2j,cx2j+1,cy2j+1)
__global__ __launch_bounds__(THREADS) void pack_kernel(
    const float* __restrict__ pred, float4* __restrict__ cxy4)
{
    const int g = blockIdx.x * THREADS + threadIdx.x;   // 0..65535, 4 preds each
    const float4* p4 = reinterpret_cast<const float4*>(pred);
    const float4 a = p4[4 * g + 0], bq = p4[4 * g + 1];
    const float4 c = p4[4 * g + 2], d  = p4[4 * g + 3];
    cxy4[2 * g + 0] = make_float4(a.x, a.y, bq.x, bq.y);
    cxy4[2 * g + 1] = make_float4(c.x, c.y, d.x, d.y);
}

// ---- Kernel 2: per-gt scan over packed centers + rank-select + epilogue ----
// XCD-swizzled task map: blockIdx%8 -> XCD (HW round-robin), so each XCD gets
// 256 consecutive tasks = 2 batches = ~0.5 MB working set (fits 4 MB L2).
__global__ __launch_bounds__(THREADS, 4) void atss_select(
    const float* __restrict__ pred,
    const float* __restrict__ gt,
    const float4* __restrict__ cxy4,
    float* __restrict__ out)
{
    __shared__ u64 cand[CAP];
    __shared__ u64 topk[KSEL];
    __shared__ int s_cnt;

    const int bid  = blockIdx.x;
    const int task = ((bid & 7) << 8) | (bid >> 3);   // 8 chunks of 256 tasks
    const int b    = task >> 7;
    const int tid  = threadIdx.x;

    const float* gtp = gt + task * 4;
    const float gcx = gtp[0], gcy = gtp[1], gw = gtp[2], gh = gtp[3];
    const float* pb = pred + (size_t)b * NPRED * 4;
    const float4* cp = cxy4 + (size_t)b * (NPRED / 2);

    float Tf = T0;
    int C = 0;
    for (int attempt = 0; attempt < 10; ++attempt) {
        if (tid == 0) s_cnt = 0;
        __syncthreads();
        const float T2 = Tf * Tf;
        // 8192 float4s (2 preds each): 4 groups x 8 loads in flight x 256 thr
        for (int base = 0; base < NPRED / 2; base += 8 * THREADS) {
            float4 v[8];
            #pragma unroll
            for (int k = 0; k < 8; ++k)
                v[k] = cp[base + k * THREADS + tid];
            #pragma unroll
            for (int k = 0; k < 8; ++k) {
                const int i0 = (base + k * THREADS + tid) * 2;
                {
                    float dx = __fsub_rn(gcx, v[k].x), dy = __fsub_rn(gcy, v[k].y);
                    if (fmaf(dx, dx, dy * dy) < T2) {
                        // numpy-exact f32 key: sqrt((dx*dx)+(dy*dy)), no FMA
                        float d = __fsqrt_rn(__fadd_rn(__fmul_rn(dx, dx),
                                                       __fmul_rn(dy, dy)));
                        int pos = atomicAdd(&s_cnt, 1);
                        if (pos < CAP)
                            cand[pos] = ((u64)__float_as_uint(d) << 32)
                                      | (unsigned)i0;
                    }
                }
                {
                    float dx = __fsub_rn(gcx, v[k].z), dy = __fsub_rn(gcy, v[k].w);
                    if (fmaf(dx, dx, dy * dy) < T2) {
                        float d = __fsqrt_rn(__fadd_rn(__fmul_rn(dx, dx),
                                                       __fmul_rn(dy, dy)));
                        int pos = atomicAdd(&s_cnt, 1);
                        if (pos < CAP)
                            cand[pos] = ((u64)__float_as_uint(d) << 32)
                                      | (unsigned)(i0 + 1);
                    }
                }
            }
        }
        __syncthreads();
        C = s_cnt;
        if (C >= KSEL && C <= CAP) break;   // ~99% exit on attempt 0
        __syncthreads();                    // protect s_cnt reset vs. reads
        Tf = (C < KSEL) ? Tf * 2.0f : Tf * 0.5f;
    }
    if (C > CAP) C = CAP;   // safety only

    // O(C^2) rank selection: unique keys -> unique ranks, top-64 sorted.
    for (int ci = tid; ci < C; ci += THREADS) {
        const u64 key = cand[ci];
        int r = 0;
        for (int j = 0; j < C; ++j)
            r += (cand[j] < key) ? 1 : 0;   // broadcast LDS read, conflict-free
        if (r < KSEL) topk[r] = key;
    }
    __syncthreads();

    if (tid < KSEL)
        epilogue(topk, pb, task, tid, gcx, gcy, gw, gh, out);
}

// ---- Fallback: full-scan per-gt kernel (strided loads), if ws too small ----
__global__ __launch_bounds__(THREADS) void atss_fullscan(
    const float* __restrict__ pred,
    const float* __restrict__ gt,
    float* __restrict__ out)
{
    __shared__ u64 cand[CAP];
    __shared__ u64 topk[KSEL];
    __shared__ int s_cnt;

    const int bid  = blockIdx.x;
    const int task = ((bid & 7) << 8) | (bid >> 3);
    const int b    = task >> 7;
    const int tid  = threadIdx.x;

    const float* gtp = gt + task * 4;
    const float gcx = gtp[0], gcy = gtp[1], gw = gtp[2], gh = gtp[3];
    const float* pb = pred + (size_t)b * NPRED * 4;
    const float2* pc = reinterpret_cast<const float2*>(pb);

    float Tf = T0;
    int C = 0;
    for (int attempt = 0; attempt < 10; ++attempt) {
        if (tid == 0) s_cnt = 0;
        __syncthreads();
        const float T2 = Tf * Tf;
        #pragma unroll 8
        for (int i = tid; i < NPRED; i += THREADS) {
            const float2 p = pc[i * 2];
            float dx = __fsub_rn(gcx, p.x), dy = __fsub_rn(gcy, p.y);
            if (fmaf(dx, dx, dy * dy) < T2) {
                float d = __fsqrt_rn(__fadd_rn(__fmul_rn(dx, dx),
                                               __fmul_rn(dy, dy)));
                int pos = atomicAdd(&s_cnt, 1);
                if (pos < CAP)
                    cand[pos] = ((u64)__float_as_uint(d) << 32) | (unsigned)i;
            }
        }
        __syncthreads();
        C = s_cnt;
        if (C >= KSEL && C <= CAP) break;
        __syncthreads();
        Tf = (C < KSEL) ? Tf * 2.0f : Tf * 0.5f;
    }
    if (C > CAP) C = CAP;

    for (int ci = tid; ci < C; ci += THREADS) {
        const u64 key = cand[ci];
        int r = 0;
        for (int j = 0; j < C; ++j)
            r += (cand[j] < key) ? 1 : 0;
        if (r < KSEL) topk[r] = key;
    }
    __syncthreads();

    if (tid < KSEL)
        epilogue(topk, pb, task, tid, gcx, gcy, gw, gh, out);
}

extern "C" void kernel_launch(void* const* d_in, const int* in_sizes, int n_in,
                              void* d_out, int out_size, void* d_ws, size_t ws_size,
                              hipStream_t stream) {
    const float* pred = (const float*)d_in[0];  // (16,16384,4) f32
    const float* gtb  = (const float*)d_in[1];  // (16,128,4)   f32
    float* out = (float*)d_out;

    if (ws_size >= (size_t)WS_NEEDED) {
        float4* cxy4 = (float4*)d_ws;
        hipLaunchKernelGGL(pack_kernel, dim3(256), dim3(THREADS), 0, stream,
                           pred, cxy4);
        hipLaunchKernelGGL(atss_select, dim3(16 * NGT), dim3(THREADS), 0, stream,
                           pred, gtb, cxy4, out);
    } else {
        hipLaunchKernelGGL(atss_fullscan, dim3(16 * NGT), dim3(THREADS), 0, stream,
                           pred, gtb, out);
    }
}

// Round 7
// 59.513 us; speedup vs baseline: 2.4744x; 2.4744x over previous
//
#include <hip/hip_runtime.h>
#include <stdint.h>

#define NPRED   16384
#define NGT     128
#define KSEL    64
#define CAP     512
#define G       4          // gts per block (register-shared scan)
#define THREADS 256
#define T0SQ    (0.055f * 0.055f)   // initial squared radius (E[C] ~ 155)

typedef unsigned long long u64;

// Outputs (float32, concatenated): ious[16*128*64], mask[...], k_idx[...]
#define OUT_IOUS 0
#define OUT_MASK (16 * NGT * KSEL)
#define OUT_KIDX (2 * 16 * NGT * KSEL)

// numpy-exact pairwise sum of 64 per-lane values (n=64: 8 strided partials,
// then ((r0+r1)+(r2+r3)) + ((r4+r5)+(r6+r7))). All lanes return the sum.
// Validated bit-exact (absmax=0) in R2-R6.
__device__ __forceinline__ float npsum64(float v, int lane) {
    const int j = lane & 7;
    float r = __shfl(v, j, 64);                       // a[j]
    #pragma unroll
    for (int k = 1; k < 8; ++k)
        r = __fadd_rn(r, __shfl(v, j + 8 * k, 64));   // += a[j+8k], in order
    const float r0 = __shfl(r, 0, 64), r1 = __shfl(r, 1, 64),
                r2 = __shfl(r, 2, 64), r3 = __shfl(r, 3, 64),
                r4 = __shfl(r, 4, 64), r5 = __shfl(r, 5, 64),
                r6 = __shfl(r, 6, 64), r7 = __shfl(r, 7, 64);
    return __fadd_rn(__fadd_rn(__fadd_rn(r0, r1), __fadd_rn(r2, r3)),
                     __fadd_rn(__fadd_rn(r4, r5), __fadd_rn(r6, r7)));
}

__global__ __launch_bounds__(THREADS) void atss_fused(
    const float* __restrict__ pred,  // [16][16384][4] cxcywh
    const float* __restrict__ gt,    // [16][128][4]  cxcywh
    float* __restrict__ out)
{
    __shared__ u64 cand[G][CAP];
    __shared__ u64 topk[G][KSEL];
    __shared__ int s_cnt[G];
    __shared__ float s_T2[G];
    __shared__ int s_active;

    const int tid  = threadIdx.x;
    const int bid  = blockIdx.x;
    const int base_task = bid * G;          // 4 consecutive gts, same batch
    const int b    = base_task >> 7;

    // gt centers for the 4 gts (block-uniform scalar loads)
    float gx[G], gy[G];
    #pragma unroll
    for (int g = 0; g < G; ++g) {
        gx[g] = gt[(base_task + g) * 4 + 0];
        gy[g] = gt[(base_task + g) * 4 + 1];
    }

    if (tid < G) { s_cnt[tid] = 0; s_T2[tid] = T0SQ; }
    if (tid == 0) s_active = (1 << G) - 1;
    __syncthreads();

    const float4* p4 = reinterpret_cast<const float4*>(pred) + (size_t)b * NPRED;

    // ---- Phase 1: register-shared scan; per-gt retry via active mask ----
    for (int attempt = 0; attempt < 10; ++attempt) {
        const int active = s_active;
        float T2[G];
        #pragma unroll
        for (int g = 0; g < G; ++g) T2[g] = s_T2[g];

        for (int base = 0; base < NPRED; base += 8 * THREADS) {
            float4 v[8];
            #pragma unroll
            for (int k = 0; k < 8; ++k)
                v[k] = p4[base + k * THREADS + tid];     // 8 loads in flight
            #pragma unroll
            for (int k = 0; k < 8; ++k) {
                const int i = base + k * THREADS + tid;
                #pragma unroll
                for (int g = 0; g < G; ++g) {
                    if (active & (1 << g)) {
                        float dx = __fsub_rn(gx[g], v[k].x);
                        float dy = __fsub_rn(gy[g], v[k].y);
                        if (fmaf(dx, dx, dy * dy) < T2[g]) {
                            // numpy-exact f32 key: sqrt((dx*dx)+(dy*dy)), no FMA
                            float d = __fsqrt_rn(__fadd_rn(__fmul_rn(dx, dx),
                                                           __fmul_rn(dy, dy)));
                            int pos = atomicAdd(&s_cnt[g], 1);
                            if (pos < CAP)
                                cand[g][pos] =
                                    ((u64)__float_as_uint(d) << 32) | (unsigned)i;
                        }
                    }
                }
            }
        }
        __syncthreads();
        if (tid == 0) {
            int na = 0;
            #pragma unroll
            for (int g = 0; g < G; ++g) {
                if (active & (1 << g)) {
                    const int C = s_cnt[g];
                    if (C < KSEL)      { s_T2[g] *= 4.0f;  s_cnt[g] = 0; na |= 1 << g; }
                    else if (C > CAP)  { s_T2[g] *= 0.25f; s_cnt[g] = 0; na |= 1 << g; }
                }
            }
            s_active = na;
        }
        __syncthreads();
        if (s_active == 0) break;
    }

    // ---- Phase 2: per-wave O(C^2) rank selection (wave w -> gt w) ----
    const int w    = tid >> 6;
    const int lane = tid & 63;
    int C = s_cnt[w]; C = C > CAP ? CAP : C;

    for (int ci = lane; ci < C; ci += 64) {
        const u64 key = cand[w][ci];
        int r = 0;
        for (int j = 0; j < C; ++j)
            r += (cand[w][j] < key) ? 1 : 0;   // broadcast LDS read, conflict-free
        if (r < KSEL) topk[w][r] = key;
    }
    asm volatile("s_waitcnt lgkmcnt(0)" ::: "memory");
    __builtin_amdgcn_wave_barrier();

    // ---- Phase 3: epilogue, wave w -> gt w, numpy-exact f32 ----
    const int task = base_task + w;
    const float* gtp = gt + task * 4;
    const float gcx = gtp[0], gcy = gtp[1], gw = gtp[2], gh = gtp[3];
    const float* pb = pred + (size_t)b * NPRED * 4;

    const u64 key = topk[w][lane];
    const int idx = (int)(key & (u64)(NPRED - 1));

    const float gx1 = __fsub_rn(gcx, __fmul_rn(0.5f, gw));
    const float gy1 = __fsub_rn(gcy, __fmul_rn(0.5f, gh));
    const float gx2 = __fadd_rn(gcx, __fmul_rn(0.5f, gw));
    const float gy2 = __fadd_rn(gcy, __fmul_rn(0.5f, gh));

    const float4 kb = *reinterpret_cast<const float4*>(pb + (size_t)idx * 4);
    const float kcx = kb.x, kcy = kb.y;
    float kx1 = __fsub_rn(kb.x, __fmul_rn(0.5f, kb.z));
    float ky1 = __fsub_rn(kb.y, __fmul_rn(0.5f, kb.w));
    float kx2 = __fadd_rn(kb.x, __fmul_rn(0.5f, kb.z));
    float ky2 = __fadd_rn(kb.y, __fmul_rn(0.5f, kb.w));
    float ltx = fmaxf(gx1, kx1), lty = fmaxf(gy1, ky1);
    float rbx = fminf(gx2, kx2), rby = fminf(gy2, ky2);
    float wx = fmaxf(__fsub_rn(rbx, ltx), 0.0f);
    float wy = fmaxf(__fsub_rn(rby, lty), 0.0f);
    float inter = __fmul_rn(wx, wy);
    float ag = __fmul_rn(__fsub_rn(gx2, gx1), __fsub_rn(gy2, gy1));
    float ak = __fmul_rn(__fsub_rn(kx2, kx1), __fsub_rn(ky2, ky1));
    float uni = __fsub_rn(__fadd_rn(ag, ak), inter);
    const float iou = __fdiv_rn(inter, uni);

    const float mean = __fdiv_rn(npsum64(iou, lane), 64.0f);
    const float dd   = __fsub_rn(iou, mean);
    const float var  = __fdiv_rn(npsum64(__fmul_rn(dd, dd), lane), 63.0f);
    const float thr  = __fadd_rn(mean, __fsqrt_rn(var));

    const bool inside = (gx1 <= kcx) && (kcx <= gx2) && (gy1 <= kcy) && (kcy <= gy2);
    const bool m = (iou >= thr) && inside;

    const int o = task * KSEL + lane;
    out[OUT_IOUS + o] = iou;
    out[OUT_MASK + o] = m ? 1.0f : 0.0f;
    out[OUT_KIDX + o] = (float)idx;
}

extern "C" void kernel_launch(void* const* d_in, const int* in_sizes, int n_in,
                              void* d_out, int out_size, void* d_ws, size_t ws_size,
                              hipStream_t stream) {
    const float* pred = (const float*)d_in[0];  // (16,16384,4) f32
    const float* gtb  = (const float*)d_in[1];  // (16,128,4)   f32
    float* out = (float*)d_out;
    hipLaunchKernelGGL(atss_fused, dim3(16 * NGT / G), dim3(THREADS), 0, stream,
                       pred, gtb, out);
}